// Round 1
// baseline (360.059 us; speedup 1.0000x reference)
//
#include <hip/hip_runtime.h>

#define NB 8
#define NN 512
#define ND 64
#define NKEEP 256
#define CJ 128

#define SELU_SCALE 1.0507009873554805f
#define SELU_ALPHA 1.6732632423543773f

__device__ __forceinline__ float fast_tanh(float z) {
    // tanh(z) = 1 - 2/(1+exp(2z)); +-overflow saturates to +-1 naturally
    return 1.0f - 2.0f / (1.0f + __expf(2.0f * z));
}

// One block per (b, i). Computes logits over all j, softmax(j), agg,
// h = agg@pwa_w + x_i@pwo_w + biases, BN + SELU, pooling score.
__global__ __launch_bounds__(256, 4)
void sast_attn_kernel(const float* __restrict__ x,
                      const float* __restrict__ att_w,
                      const float* __restrict__ att_b,
                      const float* __restrict__ att_wt,
                      const float* __restrict__ pwa_w,
                      const float* __restrict__ pwa_b,
                      const float* __restrict__ pwo_w,
                      const float* __restrict__ pwo_b,
                      const float* __restrict__ gma,
                      const float* __restrict__ bta,
                      const float* __restrict__ rmean,
                      const float* __restrict__ rvar,
                      const float* __restrict__ pool_w,
                      const float* __restrict__ pool_b,
                      float* __restrict__ ws_h,
                      float* __restrict__ ws_score)
{
    __shared__ float Xs[CJ][68];   // x[j][d]*xi[d], stride 68 (272B, 16B-aligned)
    __shared__ float xi[ND];
    __shared__ float probs[NN];    // logits -> exp() -> (wave0) agg scratch
    __shared__ float redv[4 * ND];
    __shared__ float red1[8];

    const int tid = threadIdx.x;
    const int bi  = blockIdx.x;
    const int b   = bi >> 9;
    const int i   = bi & (NN - 1);

    if (tid < ND) xi[tid] = x[(b * NN + i) * ND + tid];

    const int te = tid & 7;    // e-group: e = e0..e0+7
    const int tj = tid >> 3;   // 0..31: rows j = jb + tj + 32r
    const int e0 = te * 8;

    float attb[8], attwv[8];
    #pragma unroll
    for (int k = 0; k < 8; ++k) {
        attb[k]  = att_b[e0 + k];
        attwv[k] = att_wt[e0 + k];
    }
    __syncthreads();

    for (int c = 0; c < NN / CJ; ++c) {
        const int jb = c * CJ;
        if (c) __syncthreads();   // previous chunk's reads done before restage

        // stage Xs[j][d] = x[b][jb+j][d] * xi[d]  (float4 along d)
        #pragma unroll
        for (int r = 0; r < 8; ++r) {
            int f  = r * 256 + tid;
            int j  = f >> 4;
            int q4 = f & 15;
            float4 v = *(const float4*)(x + (b * NN + jb + j) * ND + q4 * 4);
            float4 o;
            o.x = v.x * xi[q4 * 4 + 0];
            o.y = v.y * xi[q4 * 4 + 1];
            o.z = v.z * xi[q4 * 4 + 2];
            o.w = v.w * xi[q4 * 4 + 3];
            *(float4*)(&Xs[j][q4 * 4]) = o;
        }
        __syncthreads();

        // v[j][e] = sum_d Xs[j][d] * att_w[d][e]; att_w from L1 (shared by all blocks)
        float acc[4][8];
        #pragma unroll
        for (int r = 0; r < 4; ++r)
            #pragma unroll
            for (int k = 0; k < 8; ++k) acc[r][k] = 0.f;

        #pragma unroll 2
        for (int q = 0; q < 16; ++q) {
            float4 xq[4];
            #pragma unroll
            for (int r = 0; r < 4; ++r)
                xq[r] = *(const float4*)(&Xs[tj + 32 * r][q * 4]);
            #pragma unroll
            for (int k = 0; k < 4; ++k) {
                const int d = q * 4 + k;
                float4 wa = *(const float4*)(att_w + d * ND + e0);
                float4 wb = *(const float4*)(att_w + d * ND + e0 + 4);
                #pragma unroll
                for (int r = 0; r < 4; ++r) {
                    float xv = (k == 0) ? xq[r].x : (k == 1) ? xq[r].y
                             : (k == 2) ? xq[r].z : xq[r].w;
                    acc[r][0] = fmaf(xv, wa.x, acc[r][0]);
                    acc[r][1] = fmaf(xv, wa.y, acc[r][1]);
                    acc[r][2] = fmaf(xv, wa.z, acc[r][2]);
                    acc[r][3] = fmaf(xv, wa.w, acc[r][3]);
                    acc[r][4] = fmaf(xv, wb.x, acc[r][4]);
                    acc[r][5] = fmaf(xv, wb.y, acc[r][5]);
                    acc[r][6] = fmaf(xv, wb.z, acc[r][6]);
                    acc[r][7] = fmaf(xv, wb.w, acc[r][7]);
                }
            }
        }

        // logits[j] = (sum_e tanh(v+att_b)*att_weight[e]) / TEMP
        #pragma unroll
        for (int r = 0; r < 4; ++r) {
            float p = 0.f;
            #pragma unroll
            for (int k = 0; k < 8; ++k)
                p = fmaf(fast_tanh(acc[r][k] + attb[k]), attwv[k], p);
            p += __shfl_xor(p, 1);
            p += __shfl_xor(p, 2);
            p += __shfl_xor(p, 4);
            if (te == 0) probs[jb + tj + 32 * r] = p * 0.5f;  // /TEMP
        }
    }
    __syncthreads();

    // ---- softmax over j ----
    const int wid  = tid >> 6;
    const int lane = tid & 63;
    float l0 = probs[tid], l1 = probs[tid + 256];
    float m = fmaxf(l0, l1);
    #pragma unroll
    for (int msk = 32; msk; msk >>= 1) m = fmaxf(m, __shfl_xor(m, msk));
    if (lane == 0) red1[wid] = m;
    __syncthreads();
    m = fmaxf(fmaxf(red1[0], red1[1]), fmaxf(red1[2], red1[3]));
    float p0 = __expf(l0 - m), p1 = __expf(l1 - m);
    probs[tid] = p0; probs[tid + 256] = p1;   // each thread touches only its own slots
    float ss = p0 + p1;
    #pragma unroll
    for (int msk = 32; msk; msk >>= 1) ss += __shfl_xor(ss, msk);
    if (lane == 0) red1[4 + wid] = ss;
    __syncthreads();
    const float Sinv = 1.0f / (red1[4] + red1[5] + red1[6] + red1[7]);

    // ---- agg[e] = (sum_j p_j * x[b][j][e]) * Sinv ----
    {
        float a = 0.f;
        const int j0 = wid * 128;
        #pragma unroll 4
        for (int j = 0; j < 128; ++j)
            a = fmaf(probs[j0 + j], x[(b * NN + j0 + j) * ND + lane], a);
        redv[wid * ND + lane] = a;
    }
    __syncthreads();

    // ---- wave 0: h, BN, SELU, score ----
    if (tid < ND) {
        const int e = tid;
        float aggv = (redv[e] + redv[ND + e] + redv[2 * ND + e] + redv[3 * ND + e]) * Sinv;
        probs[e] = aggv;            // only wave 0 alive in this region; in-wave LDS order ok
        float hv = pwa_b[e] + pwo_b[e];
        #pragma unroll 4
        for (int d = 0; d < ND; ++d)
            hv += probs[d] * pwa_w[d * ND + e] + xi[d] * pwo_w[d * ND + e];
        // BatchNorm (eval) + SELU
        hv = (hv - rmean[e]) * rsqrtf(rvar[e] + 1e-5f) * gma[e] + bta[e];
        hv = hv > 0.f ? SELU_SCALE * hv
                      : SELU_SCALE * SELU_ALPHA * (__expf(hv) - 1.0f);
        ws_h[(b * NN + i) * ND + e] = hv;
        float sc = hv * pool_w[e];
        #pragma unroll
        for (int msk = 32; msk; msk >>= 1) sc += __shfl_xor(sc, msk);
        if (e == 0)
            ws_score[b * NN + i] = 1.0f / (1.0f + __expf(-(sc + pool_b[0])));
    }
}

// One block per batch: exact top-k by stable rank (matches lax.top_k:
// descending values, ties broken by lower index), then gather h*score.
__global__ void sast_topk_kernel(const float* __restrict__ ws_h,
                                 const float* __restrict__ ws_score,
                                 float* __restrict__ out)
{
    __shared__ float s[NN];
    __shared__ int sel[NKEEP];
    const int b = blockIdx.x, tid = threadIdx.x;   // 512 threads
    s[tid] = ws_score[b * NN + tid];
    __syncthreads();
    const float v = s[tid];
    int rank = 0;
    for (int j = 0; j < NN; ++j) {
        float sj = s[j];
        rank += ((sj > v) || (sj == v && j < tid)) ? 1 : 0;
    }
    if (rank < NKEEP) sel[rank] = tid;
    __syncthreads();
    #pragma unroll
    for (int it = 0; it < NKEEP * ND / 512; ++it) {
        int f = it * 512 + tid;
        int k = f >> 6, e = f & 63;
        int j = sel[k];
        out[(b * NKEEP + k) * ND + e] = ws_h[(b * NN + j) * ND + e] * s[j];
    }
}

extern "C" void kernel_launch(void* const* d_in, const int* in_sizes, int n_in,
                              void* d_out, int out_size, void* d_ws, size_t ws_size,
                              hipStream_t stream)
{
    const float* x      = (const float*)d_in[0];
    const float* att_w  = (const float*)d_in[1];
    const float* att_b  = (const float*)d_in[2];
    const float* att_wt = (const float*)d_in[3];
    const float* pwa_w  = (const float*)d_in[4];
    const float* pwa_b  = (const float*)d_in[5];
    const float* pwo_w  = (const float*)d_in[6];
    const float* pwo_b  = (const float*)d_in[7];
    const float* gma    = (const float*)d_in[8];
    const float* bta    = (const float*)d_in[9];
    const float* rmean  = (const float*)d_in[10];
    const float* rvar   = (const float*)d_in[11];
    const float* pool_w = (const float*)d_in[12];
    const float* pool_b = (const float*)d_in[13];
    float* out   = (float*)d_out;
    float* ws_h  = (float*)d_ws;                 // 8*512*64 f32 = 1 MB
    float* ws_sc = ws_h + NB * NN * ND;          // 8*512 f32

    sast_attn_kernel<<<NB * NN, 256, 0, stream>>>(
        x, att_w, att_b, att_wt, pwa_w, pwa_b, pwo_w, pwo_b,
        gma, bta, rmean, rvar, pool_w, pool_b, ws_h, ws_sc);
    sast_topk_kernel<<<NB, 512, 0, stream>>>(ws_h, ws_sc, out);
}

// Round 2
// 156.948 us; speedup vs baseline: 2.2941x; 2.2941x over previous
//
#include <hip/hip_runtime.h>

#define NB 8
#define NN 512
#define ND 64
#define NKEEP 256

#define SELU_SCALE 1.0507009873554805f
#define SELU_ALPHA 1.6732632423543773f

typedef __attribute__((ext_vector_type(8))) short short8;
typedef __attribute__((ext_vector_type(4))) float f32x4;

__device__ __forceinline__ float fast_tanh(float z) {
    // tanh(z) = 1 - 2/(1+exp(2z)); saturates gracefully at +-1
    return 1.0f - __fdividef(2.0f, 1.0f + __expf(2.0f * z));
}

__device__ __forceinline__ unsigned short f2bf_rne(float f) {
    unsigned u = __float_as_uint(f);
    return (unsigned short)((u + 0x7fffu + ((u >> 16) & 1u)) >> 16);
}
__device__ __forceinline__ float bf2f(unsigned short h) {
    return __uint_as_float(((unsigned)h) << 16);
}

// One block = 4 waves = 4 consecutive i's of one batch. grid = 8*128.
// Per i: V[e][j] = sum_d (W[d][e]*x_i[d]) * X[j][d]  via bf16 hi/lo MFMA,
// logits -> fixed-shift softmax -> agg (VALU) -> h -> BN/SELU -> score.
__global__ __launch_bounds__(256, 3)
void sast_attn_kernel(const float* __restrict__ x,
                      const float* __restrict__ att_w,
                      const float* __restrict__ att_b,
                      const float* __restrict__ att_wt,
                      const float* __restrict__ pwa_w,
                      const float* __restrict__ pwa_b,
                      const float* __restrict__ pwo_w,
                      const float* __restrict__ pwo_b,
                      const float* __restrict__ gma,
                      const float* __restrict__ bta,
                      const float* __restrict__ rmean,
                      const float* __restrict__ rvar,
                      const float* __restrict__ pool_w,
                      const float* __restrict__ pool_b,
                      float* __restrict__ ws_h,
                      float* __restrict__ ws_score)
{
    __shared__ alignas(16) unsigned short Xh[128 * 64];  // 16 KB, swizzled
    __shared__ alignas(16) unsigned short Xl[128 * 64];  // 16 KB, swizzled
    __shared__ float probs[4 * NN];                      // 8 KB  (per wave)
    __shared__ float xg[4 * ND];                         // x_i per wave
    __shared__ float aggs[4 * ND];

    const int tid  = threadIdx.x;
    const int w    = tid >> 6;          // wave id = local i
    const int lane = tid & 63;
    const int g    = lane >> 4;         // k-group
    const int rr   = lane & 15;
    const int b    = blockIdx.x >> 7;
    const int i0   = (blockIdx.x & 127) * 4;
    const int i    = i0 + w;

    // ---- stage x_i for the 4 waves ----
    xg[tid] = x[(b * NN + i0 + (tid >> 6)) * ND + (tid & 63)];
    __syncthreads();

    // ---- stage chunk 0 of X into swizzled bf16 hi/lo LDS ----
    const float* xb = x + b * NN * ND;
    {
        #pragma unroll
        for (int r = 0; r < 8; ++r) {
            int f = r * 256 + tid;
            int j = f >> 4, q = f & 15;
            float4 v = *(const float4*)(xb + j * ND + q * 4);
            unsigned short h0 = f2bf_rne(v.x), h1 = f2bf_rne(v.y),
                           h2 = f2bf_rne(v.z), h3 = f2bf_rne(v.w);
            unsigned short l0 = f2bf_rne(v.x - bf2f(h0)), l1 = f2bf_rne(v.y - bf2f(h1)),
                           l2 = f2bf_rne(v.z - bf2f(h2)), l3 = f2bf_rne(v.w - bf2f(h3));
            int idx = j * 64 + ((q * 4) ^ ((j & 7) << 3));
            *(uint2*)(&Xh[idx]) = make_uint2((unsigned)h0 | ((unsigned)h1 << 16),
                                             (unsigned)h2 | ((unsigned)h3 << 16));
            *(uint2*)(&Xl[idx]) = make_uint2((unsigned)l0 | ((unsigned)l1 << 16),
                                             (unsigned)l2 | ((unsigned)l3 << 16));
        }
    }

    // ---- build W_i fragments (A-operand, [e][d]), hi/lo bf16, in registers ----
    short8 Wh[4][2], Wl[4][2];
    #pragma unroll
    for (int mt = 0; mt < 4; ++mt) {
        #pragma unroll
        for (int ks = 0; ks < 2; ++ks) {
            #pragma unroll
            for (int t = 0; t < 8; ++t) {
                int d = ks * 32 + g * 8 + t;
                int e = mt * 16 + rr;
                float wv = att_w[d * ND + e] * xg[w * ND + d];
                unsigned short hh = f2bf_rne(wv);
                unsigned short ll = f2bf_rne(wv - bf2f(hh));
                Wh[mt][ks][t] = (short)hh;
                Wl[mt][ks][t] = (short)ll;
            }
        }
    }

    // per-lane att bias / weight for e = mt*16 + g*4 + r
    f32x4 attb4[4], attw4[4];
    #pragma unroll
    for (int mt = 0; mt < 4; ++mt) {
        #pragma unroll
        for (int r = 0; r < 4; ++r) {
            int e = mt * 16 + g * 4 + r;
            attb4[mt][r] = att_b[e];
            attw4[mt][r] = att_wt[e];
        }
    }
    // fixed softmax shift: Lam = 0.5 * sum_e |att_wt[e]|  (exact bound on |logit|)
    float sab = 0.f;
    #pragma unroll
    for (int mt = 0; mt < 4; ++mt)
        #pragma unroll
        for (int r = 0; r < 4; ++r) sab += fabsf(attw4[mt][r]);
    sab += __shfl_xor(sab, 16);
    sab += __shfl_xor(sab, 32);
    const float nLam = -0.5f * sab;

    __syncthreads();   // chunk-0 staging visible

    // fragment base offsets (u16 index), swizzle folded in
    const int swz = (rr & 7) << 3;
    const int fb0 = rr * 64 + ((g * 8) ^ swz);
    const int fb1 = rr * 64 + ((g * 8 + 32) ^ swz);

    float ssum = 0.f;    // softmax denominator (unnormalized)
    float a_e  = 0.f;    // agg accumulator for e = lane

    for (int c = 0; c < 4; ++c) {
        const int jb = c * 128;

        #pragma unroll
        for (int jt = 0; jt < 8; ++jt) {
            short8 bh0 = *(const short8*)(Xh + fb0 + jt * 1024);
            short8 bh1 = *(const short8*)(Xh + fb1 + jt * 1024);
            short8 bl0 = *(const short8*)(Xl + fb0 + jt * 1024);
            short8 bl1 = *(const short8*)(Xl + fb1 + jt * 1024);
            f32x4 acc[4];
            #pragma unroll
            for (int mt = 0; mt < 4; ++mt) {
                acc[mt] = attb4[mt];
                acc[mt] = __builtin_amdgcn_mfma_f32_16x16x32_bf16(Wh[mt][0], bh0, acc[mt], 0, 0, 0);
                acc[mt] = __builtin_amdgcn_mfma_f32_16x16x32_bf16(Wh[mt][1], bh1, acc[mt], 0, 0, 0);
                acc[mt] = __builtin_amdgcn_mfma_f32_16x16x32_bf16(Wh[mt][0], bl0, acc[mt], 0, 0, 0);
                acc[mt] = __builtin_amdgcn_mfma_f32_16x16x32_bf16(Wh[mt][1], bl1, acc[mt], 0, 0, 0);
                acc[mt] = __builtin_amdgcn_mfma_f32_16x16x32_bf16(Wl[mt][0], bh0, acc[mt], 0, 0, 0);
                acc[mt] = __builtin_amdgcn_mfma_f32_16x16x32_bf16(Wl[mt][1], bh1, acc[mt], 0, 0, 0);
            }
            // logit for j = jb + jt*16 + rr : reduce over e
            float lp = 0.f;
            #pragma unroll
            for (int mt = 0; mt < 4; ++mt)
                #pragma unroll
                for (int r = 0; r < 4; ++r)
                    lp = fmaf(fast_tanh(acc[mt][r]), attw4[mt][r], lp);
            lp += __shfl_xor(lp, 16);
            lp += __shfl_xor(lp, 32);
            float p = __expf(fmaf(lp, 0.5f, nLam));   // exp(logit/TEMP - Lam) in (0,1]
            if (lane < 16) probs[w * NN + jb + jt * 16 + rr] = p;
            ssum += p;
        }

        // ---- agg: a[e=lane] += sum_j p_j * X[j][e]  (hi+lo compose) ----
        #pragma unroll 4
        for (int jj = 0; jj < 128; ++jj) {
            float p = probs[w * NN + jb + jj];
            int idx = jj * 64 + (lane ^ ((jj & 7) << 3));
            a_e = fmaf(p, bf2f(Xh[idx]), a_e);
            a_e = fmaf(p, bf2f(Xl[idx]), a_e);
        }

        if (c < 3) {
            __syncthreads();   // all waves done reading chunk c
            int jbn = (c + 1) * 128;
            #pragma unroll
            for (int r = 0; r < 8; ++r) {
                int f = r * 256 + tid;
                int j = f >> 4, q = f & 15;
                float4 v = *(const float4*)(xb + (jbn + j) * ND + q * 4);
                unsigned short h0 = f2bf_rne(v.x), h1 = f2bf_rne(v.y),
                               h2 = f2bf_rne(v.z), h3 = f2bf_rne(v.w);
                unsigned short l0 = f2bf_rne(v.x - bf2f(h0)), l1 = f2bf_rne(v.y - bf2f(h1)),
                               l2 = f2bf_rne(v.z - bf2f(h2)), l3 = f2bf_rne(v.w - bf2f(h3));
                int idx = j * 64 + ((q * 4) ^ ((j & 7) << 3));
                *(uint2*)(&Xh[idx]) = make_uint2((unsigned)h0 | ((unsigned)h1 << 16),
                                                 (unsigned)h2 | ((unsigned)h3 << 16));
                *(uint2*)(&Xl[idx]) = make_uint2((unsigned)l0 | ((unsigned)l1 << 16),
                                                 (unsigned)l2 | ((unsigned)l3 << 16));
            }
            __syncthreads();
        }
    }

    // ---- finish softmax sum (lane holds sum over {j : j%16 == rr}, x4 replicas) ----
    ssum += __shfl_xor(ssum, 1);
    ssum += __shfl_xor(ssum, 2);
    ssum += __shfl_xor(ssum, 4);
    ssum += __shfl_xor(ssum, 8);
    const float Sinv = __fdividef(1.0f, ssum);
    aggs[w * ND + lane] = a_e * Sinv;   // same-wave write->read, no barrier needed

    // ---- h = agg@pwa_w + x_i@pwo_w + biases; BN; SELU; score ----
    const int e = lane;
    float hv = pwa_b[e] + pwo_b[e];
    #pragma unroll 4
    for (int d = 0; d < ND; ++d) {
        hv = fmaf(aggs[w * ND + d], pwa_w[d * ND + e], hv);
        hv = fmaf(xg[w * ND + d],  pwo_w[d * ND + e], hv);
    }
    hv = (hv - rmean[e]) * rsqrtf(rvar[e] + 1e-5f) * gma[e] + bta[e];
    hv = hv > 0.f ? SELU_SCALE * hv
                  : SELU_SCALE * SELU_ALPHA * (__expf(hv) - 1.0f);
    ws_h[(b * NN + i) * ND + e] = hv;
    float sc = hv * pool_w[e];
    #pragma unroll
    for (int msk = 32; msk; msk >>= 1) sc += __shfl_xor(sc, msk);
    if (e == 0)
        ws_score[b * NN + i] = __fdividef(1.0f, 1.0f + __expf(-(sc + pool_b[0])));
}

// One block per batch: exact top-k by stable rank (matches lax.top_k:
// descending values, ties broken by lower index), then gather h*score.
__global__ void sast_topk_kernel(const float* __restrict__ ws_h,
                                 const float* __restrict__ ws_score,
                                 float* __restrict__ out)
{
    __shared__ float s[NN];
    __shared__ int sel[NKEEP];
    const int b = blockIdx.x, tid = threadIdx.x;   // 512 threads
    s[tid] = ws_score[b * NN + tid];
    __syncthreads();
    const float v = s[tid];
    int rank = 0;
    for (int j = 0; j < NN; ++j) {
        float sj = s[j];
        rank += ((sj > v) || (sj == v && j < tid)) ? 1 : 0;
    }
    if (rank < NKEEP) sel[rank] = tid;
    __syncthreads();
    #pragma unroll
    for (int it = 0; it < NKEEP * ND / 512; ++it) {
        int f = it * 512 + tid;
        int k = f >> 6, e = f & 63;
        int j = sel[k];
        out[(b * NKEEP + k) * ND + e] = ws_h[(b * NN + j) * ND + e] * s[j];
    }
}

extern "C" void kernel_launch(void* const* d_in, const int* in_sizes, int n_in,
                              void* d_out, int out_size, void* d_ws, size_t ws_size,
                              hipStream_t stream)
{
    const float* x      = (const float*)d_in[0];
    const float* att_w  = (const float*)d_in[1];
    const float* att_b  = (const float*)d_in[2];
    const float* att_wt = (const float*)d_in[3];
    const float* pwa_w  = (const float*)d_in[4];
    const float* pwa_b  = (const float*)d_in[5];
    const float* pwo_w  = (const float*)d_in[6];
    const float* pwo_b  = (const float*)d_in[7];
    const float* gma    = (const float*)d_in[8];
    const float* bta    = (const float*)d_in[9];
    const float* rmean  = (const float*)d_in[10];
    const float* rvar   = (const float*)d_in[11];
    const float* pool_w = (const float*)d_in[12];
    const float* pool_b = (const float*)d_in[13];
    float* out   = (float*)d_out;
    float* ws_h  = (float*)d_ws;                 // 8*512*64 f32 = 1 MB
    float* ws_sc = ws_h + NB * NN * ND;          // 8*512 f32

    sast_attn_kernel<<<NB * 128, 256, 0, stream>>>(
        x, att_w, att_b, att_wt, pwa_w, pwa_b, pwo_w, pwo_b,
        gma, bta, rmean, rvar, pool_w, pool_b, ws_h, ws_sc);
    sast_topk_kernel<<<NB, 512, 0, stream>>>(ws_h, ws_sc, out);
}